// Round 6
// baseline (638.650 us; speedup 1.0000x reference)
//
#include <hip/hip_runtime.h>
#include <hip/hip_bf16.h>
#include <stdint.h>

// Transformer decoder layer: B=256, Sd=64, Se=512, D=512, H=8, HD=64, FF=2048.
// f32 in/out; internal compute bf16 MFMA (tolerance is 2% of ref absmax).

#define SDEC 64
#define SENC 512
#define DMODEL 512
#define FFDIM 2048

typedef __bf16 bf16x8 __attribute__((ext_vector_type(8)));
typedef float  f32x4  __attribute__((ext_vector_type(4)));

static __device__ __forceinline__ float bf2f(unsigned short u) {
  union { unsigned int i; float f; } w; w.i = ((unsigned int)u) << 16; return w.f;
}
static __device__ __forceinline__ unsigned short f2bf(float f) {
  union { float f; unsigned int i; } w; w.f = f;
  unsigned int u = w.i;
  return (unsigned short)((u + 0x7fffu + ((u >> 16) & 1u)) >> 16);  // RTNE
}

// Async global->LDS, 16B per lane. LDS dest = wave-uniform base + lane*16.
static __device__ __forceinline__ void gl_lds16(const unsigned short* g, unsigned short* l) {
  __builtin_amdgcn_global_load_lds(
      (const __attribute__((address_space(1))) unsigned int*)g,
      (__attribute__((address_space(3))) unsigned int*)l,
      16, 0, 0);
}

// ---------------------------------------------------------------------------
// Shared GEMM pieces: 128x128 tile, BK=32, 4 waves, 16x16x32 MFMA, 4x4 frags.
// Epilogue swizzle: phys col = c ^ (((r>>2)&3)<<4)  -> ds_write_b16 2-way (free).
// ---------------------------------------------------------------------------
#define GEMM_COMPUTE(asrc, bsrc)                                                     \
  {                                                                                  \
    const unsigned short* as_ = (asrc);                                              \
    const unsigned short* bs_ = (bsrc);                                              \
    bf16x8 af[4], bfr[4];                                                            \
    _Pragma("unroll")                                                                \
    for (int mi = 0; mi < 4; ++mi)                                                   \
      af[mi] = *(const bf16x8*)&as_[(wm * 64 + mi * 16 + fr) * 32 + fk];             \
    _Pragma("unroll")                                                                \
    for (int ni = 0; ni < 4; ++ni)                                                   \
      bfr[ni] = *(const bf16x8*)&bs_[(wn * 64 + ni * 16 + fr) * 32 + fk];            \
    _Pragma("unroll")                                                                \
    for (int mi = 0; mi < 4; ++mi)                                                   \
      _Pragma("unroll")                                                              \
      for (int ni = 0; ni < 4; ++ni)                                                 \
        acc[mi][ni] = __builtin_amdgcn_mfma_f32_16x16x32_bf16(af[mi], bfr[ni],       \
                                                              acc[mi][ni], 0, 0, 0); \
  }

#define GEMM_EPILOGUE(RELU_)                                                          \
  {                                                                                   \
    const int fq = lane >> 4;                                                         \
    _Pragma("unroll")                                                                 \
    for (int ni = 0; ni < 4; ++ni) {                                                  \
      const int c = wn * 64 + ni * 16 + fr;                                           \
      const float bv = bias ? bias[col0 + c] : 0.f;                                   \
      _Pragma("unroll")                                                               \
      for (int mi = 0; mi < 4; ++mi) {                                                \
        _Pragma("unroll")                                                             \
        for (int t = 0; t < 4; ++t) {                                                 \
          const int r = wm * 64 + mi * 16 + fq * 4 + t;                               \
          float v = acc[mi][ni][t] + bv;                                              \
          if (RELU_) v = fmaxf(v, 0.f);                                               \
          sh[r * 128 + (c ^ (fq << 4))] = f2bf(v);  /* (r>>2)&3 == fq here */         \
        }                                                                             \
      }                                                                               \
    }                                                                                 \
    __syncthreads();                                                                  \
    const int rr = tid >> 4;          /* 0..15; (rr>>2)&3 == w (wave-uniform) */      \
    const int cc = (tid & 15) * 8;                                                    \
    _Pragma("unroll")                                                                 \
    for (int p = 0; p < 8; ++p) {                                                     \
      const int r = p * 16 + rr;                                                      \
      *(uint4*)(C + (size_t)(row0 + r) * N + col0 + cc) =                             \
          *(const uint4*)&sh[r * 128 + (cc ^ (w << 4))];                              \
    }                                                                                 \
  }

// ---------------------------------------------------------------------------
// GEMM (bf16 A): C[M,N](bf16) = A[M,K](bf16) @ B + bias, Bt[N,K] bf16.
// R4-proven loop: 2-buffer LDS dbuf, global_load_lds w=16, counted vmcnt(4),
// raw s_barrier. XCD-chunked block swizzle (grid % 8 == 0 for all launches).
// ---------------------------------------------------------------------------
template<int RELU>
__global__ __launch_bounds__(256, 2)
void gemm_kernel(const unsigned short* __restrict__ A, const unsigned short* __restrict__ Bt,
                 const float* __restrict__ bias, unsigned short* __restrict__ C,
                 int M, int N, int K)
{
  __shared__ unsigned short sh[2 * 8192];   // 2 bufs x (A 8KB | B 8KB) = 32 KB
  const int tid = threadIdx.x;

  const int gx   = gridDim.x;
  const int nwg  = gx * gridDim.y;
  const int orig = blockIdx.y * gx + blockIdx.x;
  const int wg   = (orig & 7) * (nwg >> 3) + (orig >> 3);
  const int row0 = (wg / gx) * 128;
  const int col0 = (wg % gx) * 128;

  const int w = tid >> 6, lane = tid & 63;
  const int wm = w >> 1, wn = w & 1;
  const int gr = lane >> 2, gc = (lane & 3) * 8;

  auto STAGE = [&](int k0, int buf) {
    unsigned short* as = sh + buf * 8192;
    unsigned short* bs = as + 4096;
    #pragma unroll
    for (int i = 0; i < 2; ++i) {
      const int rbase = w * 32 + i * 16;   // wave-uniform
      gl_lds16(A  + (size_t)(row0 + rbase + gr) * K + (k0 + gc), as + rbase * 32);
      gl_lds16(Bt + (size_t)(col0 + rbase + gr) * K + (k0 + gc), bs + rbase * 32);
    }
  };

  f32x4 acc[4][4];
  #pragma unroll
  for (int i = 0; i < 4; ++i)
    #pragma unroll
    for (int j = 0; j < 4; ++j)
      acc[i][j] = (f32x4){0.f, 0.f, 0.f, 0.f};

  const int fr = lane & 15, fk = (lane >> 4) * 8;

  STAGE(0, 0);
  int cur = 0;
  for (int k0 = 0; k0 + 32 < K; k0 += 32) {
    STAGE(k0 + 32, cur ^ 1);                          // prefetch next tile
    asm volatile("s_waitcnt vmcnt(4)" ::: "memory");  // own tile's loads done
    __builtin_amdgcn_s_barrier();                     // all waves: tile visible
    asm volatile("" ::: "memory");
    GEMM_COMPUTE(sh + cur * 8192, sh + cur * 8192 + 4096);
    asm volatile("" ::: "memory");
    __builtin_amdgcn_s_barrier();                     // reads of buf[cur] done
    cur ^= 1;
  }
  asm volatile("s_waitcnt vmcnt(0)" ::: "memory");
  __builtin_amdgcn_s_barrier();
  asm volatile("" ::: "memory");
  GEMM_COMPUTE(sh + cur * 8192, sh + cur * 8192 + 4096);
  asm volatile("" ::: "memory");
  __builtin_amdgcn_s_barrier();   // LDS free for epilogue reuse

  GEMM_EPILOGUE(RELU);
}

// ---------------------------------------------------------------------------
// GEMM (f32 A, fused convert): A[M,K] f32; staged via pinned inline-asm
// global_load_dwordx4 (issued one tile ahead), cvt->bf16 in regs, ds_write_b128
// just before the publish barrier (T14 issue-early/write-late). B via
// global_load_lds. vmcnt budget: 6 VM ops per tile (2 B gl_lds + 4 A loads).
// K/32 must be even (K=512 here). Same epilogue/swizzles as gemm_kernel.
// ---------------------------------------------------------------------------
template<int RELU>
__global__ __launch_bounds__(256, 2)
void gemm_a32_kernel(const float* __restrict__ A, const unsigned short* __restrict__ Bt,
                     const float* __restrict__ bias, unsigned short* __restrict__ C,
                     int M, int N, int K)
{
  __shared__ unsigned short sh[2 * 8192];   // 2 bufs x (A 8KB | B 8KB) = 32 KB
  const int tid = threadIdx.x;

  const int gx   = gridDim.x;
  const int nwg  = gx * gridDim.y;
  const int orig = blockIdx.y * gx + blockIdx.x;
  const int wg   = (orig & 7) * (nwg >> 3) + (orig >> 3);
  const int row0 = (wg / gx) * 128;
  const int col0 = (wg % gx) * 128;

  const int w = tid >> 6, lane = tid & 63;
  const int wm = w >> 1, wn = w & 1;
  const int gr = lane >> 2, gc = (lane & 3) * 8;   // B staging coords
  const int srow = tid >> 2;                       // A staging row (0..63, +64)
  const int scol = (tid & 3) * 8;                  // A staging col (floats/shorts)

  auto STAGE_B = [&](int t, int buf) {
    unsigned short* bs = sh + buf * 8192 + 4096;
    #pragma unroll
    for (int i = 0; i < 2; ++i) {
      const int rbase = w * 32 + i * 16;   // wave-uniform
      gl_lds16(Bt + (size_t)(col0 + rbase + gr) * K + (t * 32 + gc), bs + rbase * 32);
    }
  };
  auto LOAD_A = [&](int t, f32x4& o0, f32x4& o1, f32x4& o2, f32x4& o3) {
    const float* p0 = A + (size_t)(row0 + srow) * K + t * 32 + scol;
    const float* p1 = A + (size_t)(row0 + srow + 64) * K + t * 32 + scol;
    asm volatile("global_load_dwordx4 %0, %1, off"           : "=&v"(o0) : "v"(p0));
    asm volatile("global_load_dwordx4 %0, %1, off offset:16" : "=&v"(o1) : "v"(p0));
    asm volatile("global_load_dwordx4 %0, %1, off"           : "=&v"(o2) : "v"(p1));
    asm volatile("global_load_dwordx4 %0, %1, off offset:16" : "=&v"(o3) : "v"(p1));
  };
  auto WRITE_A = [&](const f32x4& a0, const f32x4& a1, const f32x4& a2, const f32x4& a3,
                     int buf) {
    unsigned short* as = sh + buf * 8192;
    union { unsigned short s[8]; uint4 v; } p;
    #pragma unroll
    for (int j = 0; j < 4; ++j) { p.s[j] = f2bf(a0[j]); p.s[4 + j] = f2bf(a1[j]); }
    *(uint4*)&as[srow * 32 + scol] = p.v;
    #pragma unroll
    for (int j = 0; j < 4; ++j) { p.s[j] = f2bf(a2[j]); p.s[4 + j] = f2bf(a3[j]); }
    *(uint4*)&as[(srow + 64) * 32 + scol] = p.v;
  };

  f32x4 acc[4][4];
  #pragma unroll
  for (int i = 0; i < 4; ++i)
    #pragma unroll
    for (int j = 0; j < 4; ++j)
      acc[i][j] = (f32x4){0.f, 0.f, 0.f, 0.f};

  const int fr = lane & 15, fk = (lane >> 4) * 8;

  f32x4 ra0, ra1, ra2, ra3, rb0, rb1, rb2, rb3;

  // prologue: tile 0 in flight (6 VM ops: 2 B + 4 A)
  STAGE_B(0, 0);
  LOAD_A(0, ra0, ra1, ra2, ra3);

  const int NT = K >> 5;   // even for all launches here
  for (int tt = 0; tt < NT; tt += 2) {
    // ---- tile tt (buf 0, regs ra) ----
    {
      STAGE_B(tt + 1, 1);
      LOAD_A(tt + 1, rb0, rb1, rb2, rb3);              // +6 VM
      asm volatile("s_waitcnt vmcnt(6)" ::: "memory"); // tile tt's 6 done
      __builtin_amdgcn_sched_barrier(0);
      WRITE_A(ra0, ra1, ra2, ra3, 0);
      asm volatile("s_waitcnt lgkmcnt(0)" ::: "memory");
      __builtin_amdgcn_sched_barrier(0);
      __builtin_amdgcn_s_barrier();                    // publish tile tt
      GEMM_COMPUTE(sh, sh + 4096);
      asm volatile("" ::: "memory");
      __builtin_amdgcn_s_barrier();                    // reads of buf0 done
    }
    // ---- tile tt+1 (buf 1, regs rb) ----
    {
      const bool pref = (tt + 2) < NT;
      if (pref) {
        STAGE_B(tt + 2, 0);
        LOAD_A(tt + 2, ra0, ra1, ra2, ra3);            // +6 VM
        asm volatile("s_waitcnt vmcnt(6)" ::: "memory");
      } else {
        asm volatile("s_waitcnt vmcnt(0)" ::: "memory");
      }
      __builtin_amdgcn_sched_barrier(0);
      WRITE_A(rb0, rb1, rb2, rb3, 1);
      asm volatile("s_waitcnt lgkmcnt(0)" ::: "memory");
      __builtin_amdgcn_sched_barrier(0);
      __builtin_amdgcn_s_barrier();                    // publish tile tt+1
      GEMM_COMPUTE(sh + 8192, sh + 8192 + 4096);
      asm volatile("" ::: "memory");
      __builtin_amdgcn_s_barrier();                    // reads of buf1 done
    }
  }

  GEMM_EPILOGUE(RELU);
}

// ---------------------------------------------------------------------------
// MFMA flash attention. One block (4 waves) per (b,h). 64 query rows, HD=64.
// XCD-chunked swizzle so same-b blocks share an XCD's L2 (KV + mask reuse).
// ---------------------------------------------------------------------------
__global__ __launch_bounds__(256, 2)
void attn_mfma(const unsigned short* __restrict__ qbuf, int qstride, int qmul,
               const unsigned short* __restrict__ kvbuf, int kvstride, int kmul, int kadd,
               int tokmul, int Skv, const float* __restrict__ mask,
               unsigned short* __restrict__ vals, float scale)
{
  __shared__ unsigned short Qs[64 * 72];   // pad 72 shorts: 144B rows, 16B-aligned
  __shared__ unsigned short Ks[64 * 72];
  __shared__ unsigned short Vt[64 * 72];   // [d][j] (transposed V tile)
  __shared__ unsigned short Ps[64 * 72];   // [row][j], wave-private 16-row slabs

  const int nwg  = gridDim.x * gridDim.y;          // 8 * B, % 8 == 0
  const int orig = blockIdx.y * gridDim.x + blockIdx.x;
  const int wg   = (orig & 7) * (nwg >> 3) + (orig >> 3);
  const int h = wg & 7, b = wg >> 3;

  const int tid = threadIdx.x;
  const int w = tid >> 6, lane = tid & 63;
  const int srow = tid >> 2;          // 0..63 staging row (token)
  const int sc0 = (tid & 3) * 16;     // 0,16,32,48 staging col (d)

  // stage Q once
  {
    const unsigned short* qg = qbuf + (size_t)(b * 64 + srow) * qstride + h * qmul + sc0;
    *(uint4*)&Qs[srow * 72 + sc0]     = *(const uint4*)qg;
    *(uint4*)&Qs[srow * 72 + sc0 + 8] = *(const uint4*)(qg + 8);
  }

  const int fr = lane & 15;    // A/B frag row index
  const int fg = lane >> 4;    // frag k-group
  const int orow = fg * 4;     // C/D row base within 16-slice

  float mstate[4], lstate[4];
  f32x4 oacc[4];
  #pragma unroll
  for (int t = 0; t < 4; ++t) { mstate[t] = -1e30f; lstate[t] = 0.f; }
  #pragma unroll
  for (int ni = 0; ni < 4; ++ni) oacc[ni] = (f32x4){0.f, 0.f, 0.f, 0.f};

  for (int j0 = 0; j0 < Skv; j0 += 64) {
    __syncthreads();  // prior tile's K/V reads complete (covers Q on iter 0)
    {
      const unsigned short* kg = kvbuf + (size_t)(b * tokmul + j0 + srow) * kvstride
                                 + h * kmul + kadd + sc0;
      *(uint4*)&Ks[srow * 72 + sc0]     = *(const uint4*)kg;
      *(uint4*)&Ks[srow * 72 + sc0 + 8] = *(const uint4*)(kg + 8);
      const unsigned short* vg = kg + 64;  // V sits 64 shorts after K
      uint4 v0 = *(const uint4*)vg;
      uint4 v1 = *(const uint4*)(vg + 8);
      const unsigned short* vsp = (const unsigned short*)&v0;
      #pragma unroll
      for (int jj = 0; jj < 8; ++jj) Vt[(sc0 + jj) * 72 + srow] = vsp[jj];
      vsp = (const unsigned short*)&v1;
      #pragma unroll
      for (int jj = 0; jj < 8; ++jj) Vt[(sc0 + 8 + jj) * 72 + srow] = vsp[jj];
    }
    __syncthreads();

    // S = Q @ K^T  (wave's 16-row slice x 64 key cols)
    f32x4 s[4];
    #pragma unroll
    for (int ni = 0; ni < 4; ++ni) s[ni] = (f32x4){0.f, 0.f, 0.f, 0.f};
    #pragma unroll
    for (int ks = 0; ks < 2; ++ks) {
      bf16x8 aq = *(const bf16x8*)&Qs[(w * 16 + fr) * 72 + ks * 32 + fg * 8];
      #pragma unroll
      for (int ni = 0; ni < 4; ++ni) {
        bf16x8 bk = *(const bf16x8*)&Ks[(ni * 16 + fr) * 72 + ks * 32 + fg * 8];
        s[ni] = __builtin_amdgcn_mfma_f32_16x16x32_bf16(aq, bk, s[ni], 0, 0, 0);
      }
    }

    // online softmax (each lane owns rows orow..orow+3 of the wave slice)
    #pragma unroll
    for (int t = 0; t < 4; ++t) {
      const int grow = w * 16 + orow + t;
      const float* mrow = mask + ((size_t)b * 64 + grow) * Skv + j0;
      float sv[4];
      float tmax = -1e30f;
      #pragma unroll
      for (int ni = 0; ni < 4; ++ni) {
        sv[ni] = s[ni][t] * scale + mrow[ni * 16 + fr];
        tmax = fmaxf(tmax, sv[ni]);
      }
      #pragma unroll
      for (int off = 1; off < 16; off <<= 1) tmax = fmaxf(tmax, __shfl_xor(tmax, off));
      const float mn = fmaxf(mstate[t], tmax);
      const float fscl = __expf(mstate[t] - mn);
      mstate[t] = mn;
      float psum = 0.f;
      #pragma unroll
      for (int ni = 0; ni < 4; ++ni) {
        float p = __expf(sv[ni] - mn);
        psum += p;
        Ps[grow * 72 + ni * 16 + fr] = f2bf(p);
      }
      #pragma unroll
      for (int off = 1; off < 16; off <<= 1) psum += __shfl_xor(psum, off);
      lstate[t] = lstate[t] * fscl + psum;
      #pragma unroll
      for (int ni = 0; ni < 4; ++ni) oacc[ni][t] *= fscl;
    }
    __syncthreads();  // Ps visible (cross-lane), Vt/Ks stable

    // O += P @ V   (A = P rows, B = Vt rows)
    #pragma unroll
    for (int ks = 0; ks < 2; ++ks) {
      bf16x8 pa = *(const bf16x8*)&Ps[(w * 16 + fr) * 72 + ks * 32 + fg * 8];
      #pragma unroll
      for (int ni = 0; ni < 4; ++ni) {
        bf16x8 vb = *(const bf16x8*)&Vt[(ni * 16 + fr) * 72 + ks * 32 + fg * 8];
        oacc[ni] = __builtin_amdgcn_mfma_f32_16x16x32_bf16(pa, vb, oacc[ni], 0, 0, 0);
      }
    }
  }

  // epilogue: normalize, write head block
  #pragma unroll
  for (int t = 0; t < 4; ++t) {
    const int grow = w * 16 + orow + t;
    const float inv = 1.f / lstate[t];
    unsigned short* og = vals + (size_t)(b * 64 + grow) * DMODEL + h * 64;
    #pragma unroll
    for (int ni = 0; ni < 4; ++ni)
      og[ni * 16 + fr] = f2bf(oacc[ni][t] * inv);
  }
}

// ---------------------------------------------------------------------------
// LayerNorm over D=512 with fused residual add. One wave per row, 8 elems/lane.
// proj input is bf16. resid32 XOR resid16 non-null; out16 and/or out32.
// ---------------------------------------------------------------------------
__global__ __launch_bounds__(256)
void ln_kernel(const unsigned short* __restrict__ proj16, const float* __restrict__ resid32,
               const unsigned short* __restrict__ resid16,
               const float* __restrict__ gamma, const float* __restrict__ beta,
               unsigned short* __restrict__ out16, float* __restrict__ out32)
{
  const int w = threadIdx.x >> 6, lane = threadIdx.x & 63;
  const size_t r = (size_t)blockIdx.x * 4 + w;
  const int d0 = lane * 8;

  float x[8];
  {
    uint4 u = *(const uint4*)(proj16 + r * DMODEL + d0);
    const unsigned short* s = (const unsigned short*)&u;
    #pragma unroll
    for (int j = 0; j < 8; ++j) x[j] = bf2f(s[j]);
  }
  if (resid32) {
    const float* p = resid32 + r * DMODEL + d0;
    float4 a = *(const float4*)p, b = *(const float4*)(p + 4);
    x[0] += a.x; x[1] += a.y; x[2] += a.z; x[3] += a.w;
    x[4] += b.x; x[5] += b.y; x[6] += b.z; x[7] += b.w;
  } else {
    uint4 u = *(const uint4*)(resid16 + r * DMODEL + d0);
    const unsigned short* s = (const unsigned short*)&u;
    #pragma unroll
    for (int j = 0; j < 8; ++j) x[j] += bf2f(s[j]);
  }

  float sum = 0.f;
  #pragma unroll
  for (int j = 0; j < 8; ++j) sum += x[j];
  #pragma unroll
  for (int off = 32; off > 0; off >>= 1) sum += __shfl_xor(sum, off);
  const float mean = sum * (1.f / DMODEL);

  float vs = 0.f;
  #pragma unroll
  for (int j = 0; j < 8; ++j) { float t = x[j] - mean; vs += t * t; }
  #pragma unroll
  for (int off = 32; off > 0; off >>= 1) vs += __shfl_xor(vs, off);
  const float rstd = rsqrtf(vs * (1.f / DMODEL) + 1e-5f);

  float4 g0 = *(const float4*)(gamma + d0), g1 = *(const float4*)(gamma + d0 + 4);
  float4 b0 = *(const float4*)(beta + d0),  b1 = *(const float4*)(beta + d0 + 4);
  const float g[8]  = {g0.x, g0.y, g0.z, g0.w, g1.x, g1.y, g1.z, g1.w};
  const float bb[8] = {b0.x, b0.y, b0.z, b0.w, b1.x, b1.y, b1.z, b1.w};
  float y[8];
  #pragma unroll
  for (int j = 0; j < 8; ++j) y[j] = g[j] * (x[j] - mean) * rstd + bb[j];

  if (out16) {
    union { unsigned short s[8]; uint4 v; } p;
    #pragma unroll
    for (int j = 0; j < 8; ++j) p.s[j] = f2bf(y[j]);
    *(uint4*)(out16 + r * DMODEL + d0) = p.v;
  }
  if (out32) {
    float* o = out32 + r * DMODEL + d0;
    *(float4*)o       = (float4){y[0], y[1], y[2], y[3]};
    *(float4*)(o + 4) = (float4){y[4], y[5], y[6], y[7]};
  }
}

// ---------------------------------------------------------------------------
// Transpose + f32->bf16 convert: W[K,N] f32 -> Wt[N,K] bf16. 32x32 LDS tiles.
// ---------------------------------------------------------------------------
__global__ __launch_bounds__(256)
void transpose_cvt(const float* __restrict__ W, unsigned short* __restrict__ Wt,
                   int K, int N)
{
  __shared__ float tile[32][33];
  const int tx = threadIdx.x, ty = threadIdx.y;
  const int n = blockIdx.x * 32 + tx;
  #pragma unroll
  for (int rr = 0; rr < 4; ++rr) {
    const int k = blockIdx.y * 32 + ty + rr * 8;
    tile[ty + rr * 8][tx] = W[(size_t)k * N + n];
  }
  __syncthreads();
  const int k2 = blockIdx.y * 32 + tx;
  #pragma unroll
  for (int rr = 0; rr < 4; ++rr) {
    const int n2 = blockIdx.x * 32 + ty + rr * 8;
    Wt[(size_t)n2 * K + k2] = f2bf(tile[tx][ty + rr * 8]);
  }
}

// ---------------------------------------------------------------------------
extern "C" void kernel_launch(void* const* d_in, const int* in_sizes, int n_in,
                              void* d_out, int out_size, void* d_ws, size_t ws_size,
                              hipStream_t stream)
{
  const float* x        = (const float*)d_in[0];
  const float* y        = (const float*)d_in[1];
  const float* mask     = (const float*)d_in[2];
  const float* mask2    = (const float*)d_in[3];
  const float* qkv_w    = (const float*)d_in[4];
  const float* qkv_b    = (const float*)d_in[5];
  const float* sa_out_w = (const float*)d_in[6];
  const float* sa_out_b = (const float*)d_in[7];
  const float* q_w      = (const float*)d_in[8];
  const float* q_b      = (const float*)d_in[9];
  const float* kv_w     = (const float*)d_in[10];
  const float* kv_b     = (const float*)d_in[11];
  const float* ca_out_w = (const float*)d_in[12];
  const float* ca_out_b = (const float*)d_in[13];
  const float* l1_w     = (const float*)d_in[14];
  const float* l1_b     = (const float*)d_in[15];
  const float* l2_w     = (const float*)d_in[16];
  const float* l2_b     = (const float*)d_in[17];
  const float* g1 = (const float*)d_in[18];
  const float* b1 = (const float*)d_in[19];
  const float* g2 = (const float*)d_in[20];
  const float* b2 = (const float*)d_in[21];
  const float* g3 = (const float*)d_in[22];
  const float* b3 = (const float*)d_in[23];

  const int B  = in_sizes[1] / (SDEC * DMODEL);   // 256
  const int M  = B * SDEC;                        // 16384 decoder tokens
  const int ME = B * SENC;                        // 131072 encoder tokens

  char* ws = (char*)d_ws;
  size_t off = 0;
  auto alloc = [&](size_t bytes) -> char* {
    char* p = ws + off;
    off += (bytes + 255) & ~(size_t)255;
    return p;
  };
  // persistent regions
  unsigned short* qkv_wt = (unsigned short*)alloc((size_t)1536 * 512 * 2);
  unsigned short* sa_wt  = (unsigned short*)alloc((size_t)512 * 512 * 2);
  unsigned short* q_wt   = (unsigned short*)alloc((size_t)512 * 512 * 2);
  unsigned short* kv_wt  = (unsigned short*)alloc((size_t)1024 * 512 * 2);
  unsigned short* ca_wt  = (unsigned short*)alloc((size_t)512 * 512 * 2);
  unsigned short* l1_wt  = (unsigned short*)alloc((size_t)2048 * 512 * 2);
  unsigned short* l2_wt  = (unsigned short*)alloc((size_t)512 * 2048 * 2);
  unsigned short* kvb    = (unsigned short*)alloc((size_t)ME * 1024 * 2);  // 256 MiB
  char*           xreg   = alloc((size_t)ME * 512 * 2);                    // 128 MiB region
  // xreg aliases (qkvb dead after self-attn):
  unsigned short* qkvb   = (unsigned short*)xreg;                          // 48 MiB
  unsigned short* qb     = (unsigned short*)xreg;                          // 16 MiB (after self-attn)
  unsigned short* y2b    = (unsigned short*)(xreg + (size_t)16777216);     // @16 MiB
  unsigned short* valsb  = (unsigned short*)(xreg + (size_t)50331648);     // @48 MiB
  unsigned short* proj   = (unsigned short*)(xreg + (size_t)67108864);     // @64 MiB (bf16)
  unsigned short* y1b    = (unsigned short*)(xreg + (size_t)100663296);    // @96 MiB
  unsigned short* hb     = kvb;  // FFN hidden aliases kv (kv dead after cross-attn)
  (void)ws_size; (void)n_in; (void)out_size;

  // --- weight transposes (f32 [K,N] -> bf16 [N,K]) ---
  dim3 tb(32, 8);
  transpose_cvt<<<dim3(1536 / 32, 512 / 32), tb, 0, stream>>>(qkv_w, qkv_wt, 512, 1536);
  transpose_cvt<<<dim3(512 / 32, 512 / 32), tb, 0, stream>>>(sa_out_w, sa_wt, 512, 512);
  transpose_cvt<<<dim3(512 / 32, 512 / 32), tb, 0, stream>>>(q_w, q_wt, 512, 512);
  transpose_cvt<<<dim3(1024 / 32, 512 / 32), tb, 0, stream>>>(kv_w, kv_wt, 512, 1024);
  transpose_cvt<<<dim3(512 / 32, 512 / 32), tb, 0, stream>>>(ca_out_w, ca_wt, 512, 512);
  transpose_cvt<<<dim3(2048 / 32, 512 / 32), tb, 0, stream>>>(l1_w, l1_wt, 512, 2048);
  transpose_cvt<<<dim3(512 / 32, 2048 / 32), tb, 0, stream>>>(l2_w, l2_wt, 2048, 512);

  const float scale = 0.125f;  // 1/sqrt(64)

  // --- kv projection (f32 x read directly; cvt fused into A-staging) ---
  gemm_a32_kernel<0><<<dim3(1024 / 128, ME / 128), 256, 0, stream>>>(x, kv_wt, kv_b, kvb, ME, 1024, 512);

  // --- self attention ---
  gemm_a32_kernel<0><<<dim3(1536 / 128, M / 128), 256, 0, stream>>>(y, qkv_wt, qkv_b, qkvb, M, 1536, 512);
  // qkv row layout per token: head h -> [h*192 .. ): q(64) | k(64) | v(64)
  attn_mfma<<<dim3(8, B), 256, 0, stream>>>(qkvb, 1536, 192, qkvb, 1536, 192, 64, SDEC, SDEC, mask, valsb, scale);
  gemm_kernel<0><<<dim3(512 / 128, M / 128), 256, 0, stream>>>(valsb, sa_wt, sa_out_b, proj, M, 512, 512);
  ln_kernel<<<M / 4, 256, 0, stream>>>(proj, y, nullptr, g1, b1, y1b, nullptr);

  // --- cross attention ---
  gemm_kernel<0><<<dim3(512 / 128, M / 128), 256, 0, stream>>>(y1b, q_wt, q_b, qb, M, 512, 512);
  // kv row layout per token: head h -> [h*128 .. ): k(64) | v(64)
  attn_mfma<<<dim3(8, B), 256, 0, stream>>>(qb, 512, 64, kvb, 1024, 128, 0, SENC, SENC, mask2, valsb, scale);
  gemm_kernel<0><<<dim3(512 / 128, M / 128), 256, 0, stream>>>(valsb, ca_wt, ca_out_b, proj, M, 512, 512);
  ln_kernel<<<M / 4, 256, 0, stream>>>(proj, nullptr, y1b, g2, b2, y2b, nullptr);

  // --- FFN ---
  gemm_kernel<1><<<dim3(2048 / 128, M / 128), 256, 0, stream>>>(y2b, l1_wt, l1_b, hb, M, 2048, 512);
  gemm_kernel<0><<<dim3(512 / 128, M / 128), 256, 0, stream>>>(hb, l2_wt, l2_b, proj, M, 512, 2048);
  ln_kernel<<<M / 4, 256, 0, stream>>>(proj, nullptr, y2b, g3, b3, nullptr, (float*)d_out);
}

// Round 7
// 624.056 us; speedup vs baseline: 1.0234x; 1.0234x over previous
//
#include <hip/hip_runtime.h>
#include <hip/hip_bf16.h>
#include <stdint.h>

// Transformer decoder layer: B=256, Sd=64, Se=512, D=512, H=8, HD=64, FF=2048.
// f32 in/out; internal compute bf16 MFMA (tolerance is 2% of ref absmax).

#define SDEC 64
#define SENC 512
#define DMODEL 512
#define FFDIM 2048

typedef __bf16 bf16x8 __attribute__((ext_vector_type(8)));
typedef float  f32x4  __attribute__((ext_vector_type(4)));

static __device__ __forceinline__ float bf2f(unsigned short u) {
  union { unsigned int i; float f; } w; w.i = ((unsigned int)u) << 16; return w.f;
}
static __device__ __forceinline__ unsigned short f2bf(float f) {
  union { float f; unsigned int i; } w; w.f = f;
  unsigned int u = w.i;
  return (unsigned short)((u + 0x7fffu + ((u >> 16) & 1u)) >> 16);  // RTNE
}

// Async global->LDS, 16B per lane. LDS dest = wave-uniform base + lane*16.
static __device__ __forceinline__ void gl_lds16(const unsigned short* g, unsigned short* l) {
  __builtin_amdgcn_global_load_lds(
      (const __attribute__((address_space(1))) unsigned int*)g,
      (__attribute__((address_space(3))) unsigned int*)l,
      16, 0, 0);
}

// ---------------------------------------------------------------------------
// f32 -> bf16 elementwise convert (RTNE), 8 elems/thread/iter, grid-stride.
// ---------------------------------------------------------------------------
__global__ __launch_bounds__(256)
void cvt_f32_bf16(const float* __restrict__ in, unsigned short* __restrict__ out, size_t n8)
{
  size_t i = (size_t)blockIdx.x * blockDim.x + threadIdx.x;
  const size_t stride = (size_t)gridDim.x * blockDim.x;
  for (; i < n8; i += stride) {
    const float* p = in + i * 8;
    float4 a = *(const float4*)p, b = *(const float4*)(p + 4);
    union { unsigned short s[8]; uint4 v; } u;
    u.s[0] = f2bf(a.x); u.s[1] = f2bf(a.y); u.s[2] = f2bf(a.z); u.s[3] = f2bf(a.w);
    u.s[4] = f2bf(b.x); u.s[5] = f2bf(b.y); u.s[6] = f2bf(b.z); u.s[7] = f2bf(b.w);
    *(uint4*)(out + i * 8) = u.v;
  }
}

// ---------------------------------------------------------------------------
// 128x128 GEMM (proven R4 structure + epilogue swizzle). Used for N=512 / odd
// shapes. 2-buffer LDS dbuf, gl_lds w=16, counted vmcnt(4), raw s_barrier.
// ---------------------------------------------------------------------------
#define GEMM_COMPUTE(asrc, bsrc)                                                     \
  {                                                                                  \
    const unsigned short* as_ = (asrc);                                              \
    const unsigned short* bs_ = (bsrc);                                              \
    bf16x8 af[4], bfr[4];                                                            \
    _Pragma("unroll")                                                                \
    for (int mi = 0; mi < 4; ++mi)                                                   \
      af[mi] = *(const bf16x8*)&as_[(wm * 64 + mi * 16 + fr) * 32 + fk];             \
    _Pragma("unroll")                                                                \
    for (int ni = 0; ni < 4; ++ni)                                                   \
      bfr[ni] = *(const bf16x8*)&bs_[(wn * 64 + ni * 16 + fr) * 32 + fk];            \
    _Pragma("unroll")                                                                \
    for (int mi = 0; mi < 4; ++mi)                                                   \
      _Pragma("unroll")                                                              \
      for (int ni = 0; ni < 4; ++ni)                                                 \
        acc[mi][ni] = __builtin_amdgcn_mfma_f32_16x16x32_bf16(af[mi], bfr[ni],       \
                                                              acc[mi][ni], 0, 0, 0); \
  }

template<int RELU>
__global__ __launch_bounds__(256, 2)
void gemm_kernel(const unsigned short* __restrict__ A, const unsigned short* __restrict__ Bt,
                 const float* __restrict__ bias, unsigned short* __restrict__ C,
                 int M, int N, int K)
{
  __shared__ unsigned short sh[2 * 8192];   // 2 bufs x (A 8KB | B 8KB) = 32 KB
  const int tid = threadIdx.x;

  const int gx   = gridDim.x;
  const int nwg  = gx * gridDim.y;
  const int orig = blockIdx.y * gx + blockIdx.x;
  const int wg   = (orig & 7) * (nwg >> 3) + (orig >> 3);
  const int row0 = (wg / gx) * 128;
  const int col0 = (wg % gx) * 128;

  const int w = tid >> 6, lane = tid & 63;
  const int wm = w >> 1, wn = w & 1;
  const int gr = lane >> 2, gc = (lane & 3) * 8;

  auto STAGE = [&](int k0, int buf) {
    unsigned short* as = sh + buf * 8192;
    unsigned short* bs = as + 4096;
    #pragma unroll
    for (int i = 0; i < 2; ++i) {
      const int rbase = w * 32 + i * 16;   // wave-uniform
      gl_lds16(A  + (size_t)(row0 + rbase + gr) * K + (k0 + gc), as + rbase * 32);
      gl_lds16(Bt + (size_t)(col0 + rbase + gr) * K + (k0 + gc), bs + rbase * 32);
    }
  };

  f32x4 acc[4][4];
  #pragma unroll
  for (int i = 0; i < 4; ++i)
    #pragma unroll
    for (int j = 0; j < 4; ++j)
      acc[i][j] = (f32x4){0.f, 0.f, 0.f, 0.f};

  const int fr = lane & 15, fk = (lane >> 4) * 8;

  STAGE(0, 0);
  int cur = 0;
  for (int k0 = 0; k0 + 32 < K; k0 += 32) {
    STAGE(k0 + 32, cur ^ 1);                          // prefetch next tile
    asm volatile("s_waitcnt vmcnt(4)" ::: "memory");  // own tile's loads done
    __builtin_amdgcn_s_barrier();                     // all waves: tile visible
    asm volatile("" ::: "memory");
    GEMM_COMPUTE(sh + cur * 8192, sh + cur * 8192 + 4096);
    asm volatile("" ::: "memory");
    __builtin_amdgcn_s_barrier();                     // reads of buf[cur] done
    cur ^= 1;
  }
  asm volatile("s_waitcnt vmcnt(0)" ::: "memory");
  __builtin_amdgcn_s_barrier();
  asm volatile("" ::: "memory");
  GEMM_COMPUTE(sh + cur * 8192, sh + cur * 8192 + 4096);
  asm volatile("" ::: "memory");
  __builtin_amdgcn_s_barrier();   // LDS free for epilogue reuse

  // Epilogue: LDS-staged, swizzled (phys col = c ^ (fq<<4); 2-way = free).
  {
    const int fq = lane >> 4;
    #pragma unroll
    for (int ni = 0; ni < 4; ++ni) {
      const int c = wn * 64 + ni * 16 + fr;
      const float bv = bias ? bias[col0 + c] : 0.f;
      #pragma unroll
      for (int mi = 0; mi < 4; ++mi) {
        #pragma unroll
        for (int t = 0; t < 4; ++t) {
          const int r = wm * 64 + mi * 16 + fq * 4 + t;
          float v = acc[mi][ni][t] + bv;
          if (RELU) v = fmaxf(v, 0.f);
          sh[r * 128 + (c ^ (fq << 4))] = f2bf(v);
        }
      }
    }
    __syncthreads();
    const int rr = tid >> 4;
    const int cc = (tid & 15) * 8;
    #pragma unroll
    for (int p = 0; p < 8; ++p) {
      const int r = p * 16 + rr;
      *(uint4*)(C + (size_t)(row0 + r) * N + col0 + cc) =
          *(const uint4*)&sh[r * 128 + (cc ^ (w << 4))];
    }
  }
}

// ---------------------------------------------------------------------------
// 256x256 8-phase GEMM (m201 template port). 512 threads (8 waves, 2M x 4N),
// BK=64, 128 KB LDS double-buffer. Per wave: 128x64 output = acc[8][4] f32x4.
// K-loop: per tile, 4 phases of {8 ds_read || staged gl_lds -> s_barrier ->
// setprio(1) 16 MFMA setprio(0) -> s_barrier}; per-wave exact vmcnt drain at
// tile top (only own tile's 8 loads outstanding). T2 XOR swizzle both-sides:
// LDS phys 16B-chunk = logical ^ (row&7); staging pre-swizzles the GLOBAL
// source (rule #21), reads apply the same XOR -> ds_read_b128 conflict-free.
// Requires M%256==0, N%256==0, K%64==0, grid%8==0.
// ---------------------------------------------------------------------------
template<int RELU>
__global__ __launch_bounds__(512, 1)
void gemm256_kernel(const unsigned short* __restrict__ A, const unsigned short* __restrict__ Bt,
                    const float* __restrict__ bias, unsigned short* __restrict__ C,
                    int M, int N, int K)
{
  __shared__ unsigned short sh[65536];   // 2 bufs x (A 32KB | B 32KB) = 128 KB
  const int tid = threadIdx.x;

  const int gx   = gridDim.x;
  const int nwg  = gx * gridDim.y;
  const int orig = blockIdx.y * gx + blockIdx.x;
  const int wg   = (orig & 7) * (nwg >> 3) + (orig >> 3);
  const int row0 = (wg / gx) * 256;
  const int col0 = (wg % gx) * 256;

  const int w = tid >> 6, lane = tid & 63;
  const int wm = w >> 2, wn = w & 3;            // 2 x 4 wave grid
  const int fr = lane & 15, fg = lane >> 4;

  // staging: lane l covers row (+l>>3) chunk (l&7); source chunk pre-swizzled
  const int srl = lane >> 3;                    // 0..7 sub-row
  const int sgc = ((lane & 7) ^ srl) * 8;       // global col offset (shorts)

  // stage one quarter of tile (2 gl_lds): parts 0,1 = A halves; 2,3 = B halves
  auto STAGE_PART = [&](int k0, int buf, int part) {
    unsigned short* base = sh + buf * 32768 + ((part >= 2) ? 16384 : 0);
    const unsigned short* G = (part >= 2) ? Bt : A;
    const int o0 = (part >= 2) ? col0 : row0;
    const int ph = part & 1;
    #pragma unroll
    for (int j = 0; j < 2; ++j) {
      const int rt = w * 32 + ph * 16 + j * 8;  // wave-uniform row in tile
      gl_lds16(G + (size_t)(o0 + rt + srl) * K + (k0 + sgc), base + rt * 64);
    }
  };

  f32x4 acc[8][4];
  #pragma unroll
  for (int i = 0; i < 8; ++i)
    #pragma unroll
    for (int j = 0; j < 4; ++j)
      acc[i][j] = (f32x4){0.f, 0.f, 0.f, 0.f};

  const int NT = K >> 6;
  #pragma unroll
  for (int part = 0; part < 4; ++part) STAGE_PART(0, 0, part);   // tile 0 -> buf 0

  for (int t = 0; t < NT; ++t) {
    const int buf = t & 1;
    const unsigned short* as = sh + buf * 32768;
    const unsigned short* bs = as + 16384;
    const int kn = (t + 1) << 6;
    // only own tile's 8 loads outstanding -> exact drain
    asm volatile("s_waitcnt vmcnt(0)" ::: "memory");
    __builtin_amdgcn_sched_barrier(0);
    __builtin_amdgcn_s_barrier();                 // tile t visible to all waves

    #pragma unroll
    for (int ks = 0; ks < 2; ++ks) {
      #pragma unroll
      for (int mh = 0; mh < 2; ++mh) {
        bf16x8 af[4], bfv[4];
        #pragma unroll
        for (int i = 0; i < 4; ++i) {
          const int row = wm * 128 + (mh * 4 + i) * 16 + fr;
          af[i] = *(const bf16x8*)&as[row * 64 + (((ks * 4 + fg) ^ (fr & 7)) * 8)];
        }
        #pragma unroll
        for (int i = 0; i < 4; ++i) {
          const int row = wn * 64 + i * 16 + fr;
          bfv[i] = *(const bf16x8*)&bs[row * 64 + (((ks * 4 + fg) ^ (fr & 7)) * 8)];
        }
        // stage next tile early (phases 0,1) so loads fly under 3 phases of MFMA
        if (t + 1 < NT) {
          const int ph = ks * 2 + mh;
          if (ph == 0) { STAGE_PART(kn, buf ^ 1, 0); STAGE_PART(kn, buf ^ 1, 1); }
          if (ph == 1) { STAGE_PART(kn, buf ^ 1, 2); STAGE_PART(kn, buf ^ 1, 3); }
        }
        asm volatile("" ::: "memory");
        __builtin_amdgcn_s_barrier();             // phase: reads issued everywhere
        __builtin_amdgcn_s_setprio(1);
        #pragma unroll
        for (int i = 0; i < 4; ++i)
          #pragma unroll
          for (int j = 0; j < 4; ++j)
            acc[mh * 4 + i][j] = __builtin_amdgcn_mfma_f32_16x16x32_bf16(
                af[i], bfv[j], acc[mh * 4 + i][j], 0, 0, 0);
        __builtin_amdgcn_s_setprio(0);
        asm volatile("" ::: "memory");
        __builtin_amdgcn_s_barrier();             // phase end
      }
    }
  }

  // Epilogue: 256x256 bf16 tile staged in sh (128 KB), swizzled; coalesced copy.
  {
    #pragma unroll
    for (int j = 0; j < 4; ++j) {
      const int c = wn * 64 + j * 16 + fr;
      const float bv = bias ? bias[col0 + c] : 0.f;
      const int cp = c ^ (fg << 4);   // (r>>2)&3 == fg for all rows below
      #pragma unroll
      for (int i = 0; i < 8; ++i) {
        #pragma unroll
        for (int tt = 0; tt < 4; ++tt) {
          const int r = wm * 128 + i * 16 + fg * 4 + tt;
          float v = acc[i][j][tt] + bv;
          if (RELU) v = fmaxf(v, 0.f);
          sh[r * 256 + cp] = f2bf(v);
        }
      }
    }
    __syncthreads();
    const int rr = tid >> 5;          // 0..15
    const int cc = (tid & 31) * 8;    // 32 lanes x 8 shorts = 512B per row
    #pragma unroll
    for (int p = 0; p < 16; ++p) {
      const int r = p * 16 + rr;
      const int rc = (r >> 2) & 3;
      *(uint4*)(C + (size_t)(row0 + r) * N + col0 + cc) =
          *(const uint4*)&sh[r * 256 + (cc ^ (rc << 4))];
    }
  }
}

// ---------------------------------------------------------------------------
// MFMA flash attention. One block (4 waves) per (b,h). 64 query rows, HD=64.
// XCD-chunked swizzle so same-b blocks share an XCD's L2 (KV + mask reuse).
// ---------------------------------------------------------------------------
__global__ __launch_bounds__(256, 2)
void attn_mfma(const unsigned short* __restrict__ qbuf, int qstride, int qmul,
               const unsigned short* __restrict__ kvbuf, int kvstride, int kmul, int kadd,
               int tokmul, int Skv, const float* __restrict__ mask,
               unsigned short* __restrict__ vals, float scale)
{
  __shared__ unsigned short Qs[64 * 72];   // pad 72 shorts: 144B rows, 16B-aligned
  __shared__ unsigned short Ks[64 * 72];
  __shared__ unsigned short Vt[64 * 72];   // [d][j] (transposed V tile)
  __shared__ unsigned short Ps[64 * 72];   // [row][j], wave-private 16-row slabs

  const int nwg  = gridDim.x * gridDim.y;          // 8 * B, % 8 == 0
  const int orig = blockIdx.y * gridDim.x + blockIdx.x;
  const int wg   = (orig & 7) * (nwg >> 3) + (orig >> 3);
  const int h = wg & 7, b = wg >> 3;

  const int tid = threadIdx.x;
  const int w = tid >> 6, lane = tid & 63;
  const int srow = tid >> 2;          // 0..63 staging row (token)
  const int sc0 = (tid & 3) * 16;     // 0,16,32,48 staging col (d)

  // stage Q once
  {
    const unsigned short* qg = qbuf + (size_t)(b * 64 + srow) * qstride + h * qmul + sc0;
    *(uint4*)&Qs[srow * 72 + sc0]     = *(const uint4*)qg;
    *(uint4*)&Qs[srow * 72 + sc0 + 8] = *(const uint4*)(qg + 8);
  }

  const int fr = lane & 15;    // A/B frag row index
  const int fg = lane >> 4;    // frag k-group
  const int orow = fg * 4;     // C/D row base within 16-slice

  float mstate[4], lstate[4];
  f32x4 oacc[4];
  #pragma unroll
  for (int t = 0; t < 4; ++t) { mstate[t] = -1e30f; lstate[t] = 0.f; }
  #pragma unroll
  for (int ni = 0; ni < 4; ++ni) oacc[ni] = (f32x4){0.f, 0.f, 0.f, 0.f};

  for (int j0 = 0; j0 < Skv; j0 += 64) {
    __syncthreads();  // prior tile's K/V reads complete (covers Q on iter 0)
    {
      const unsigned short* kg = kvbuf + (size_t)(b * tokmul + j0 + srow) * kvstride
                                 + h * kmul + kadd + sc0;
      *(uint4*)&Ks[srow * 72 + sc0]     = *(const uint4*)kg;
      *(uint4*)&Ks[srow * 72 + sc0 + 8] = *(const uint4*)(kg + 8);
      const unsigned short* vg = kg + 64;  // V sits 64 shorts after K
      uint4 v0 = *(const uint4*)vg;
      uint4 v1 = *(const uint4*)(vg + 8);
      const unsigned short* vsp = (const unsigned short*)&v0;
      #pragma unroll
      for (int jj = 0; jj < 8; ++jj) Vt[(sc0 + jj) * 72 + srow] = vsp[jj];
      vsp = (const unsigned short*)&v1;
      #pragma unroll
      for (int jj = 0; jj < 8; ++jj) Vt[(sc0 + 8 + jj) * 72 + srow] = vsp[jj];
    }
    __syncthreads();

    // S = Q @ K^T  (wave's 16-row slice x 64 key cols)
    f32x4 s[4];
    #pragma unroll
    for (int ni = 0; ni < 4; ++ni) s[ni] = (f32x4){0.f, 0.f, 0.f, 0.f};
    #pragma unroll
    for (int ks = 0; ks < 2; ++ks) {
      bf16x8 aq = *(const bf16x8*)&Qs[(w * 16 + fr) * 72 + ks * 32 + fg * 8];
      #pragma unroll
      for (int ni = 0; ni < 4; ++ni) {
        bf16x8 bk = *(const bf16x8*)&Ks[(ni * 16 + fr) * 72 + ks * 32 + fg * 8];
        s[ni] = __builtin_amdgcn_mfma_f32_16x16x32_bf16(aq, bk, s[ni], 0, 0, 0);
      }
    }

    // online softmax (each lane owns rows orow..orow+3 of the wave slice)
    #pragma unroll
    for (int t = 0; t < 4; ++t) {
      const int grow = w * 16 + orow + t;
      const float* mrow = mask + ((size_t)b * 64 + grow) * Skv + j0;
      float sv[4];
      float tmax = -1e30f;
      #pragma unroll
      for (int ni = 0; ni < 4; ++ni) {
        sv[ni] = s[ni][t] * scale + mrow[ni * 16 + fr];
        tmax = fmaxf(tmax, sv[ni]);
      }
      #pragma unroll
      for (int off = 1; off < 16; off <<= 1) tmax = fmaxf(tmax, __shfl_xor(tmax, off));
      const float mn = fmaxf(mstate[t], tmax);
      const float fscl = __expf(mstate[t] - mn);
      mstate[t] = mn;
      float psum = 0.f;
      #pragma unroll
      for (int ni = 0; ni < 4; ++ni) {
        float p = __expf(sv[ni] - mn);
        psum += p;
        Ps[grow * 72 + ni * 16 + fr] = f2bf(p);
      }
      #pragma unroll
      for (int off = 1; off < 16; off <<= 1) psum += __shfl_xor(psum, off);
      lstate[t] = lstate[t] * fscl + psum;
      #pragma unroll
      for (int ni = 0; ni < 4; ++ni) oacc[ni][t] *= fscl;
    }
    __syncthreads();  // Ps visible (cross-lane), Vt/Ks stable

    // O += P @ V   (A = P rows, B = Vt rows)
    #pragma unroll
    for (int ks = 0; ks < 2; ++ks) {
      bf16x8 pa = *(const bf16x8*)&Ps[(w * 16 + fr) * 72 + ks * 32 + fg * 8];
      #pragma unroll
      for (int ni = 0; ni < 4; ++ni) {
        bf16x8 vb = *(const bf16x8*)&Vt[(ni * 16 + fr) * 72 + ks * 32 + fg * 8];
        oacc[ni] = __builtin_amdgcn_mfma_f32_16x16x32_bf16(pa, vb, oacc[ni], 0, 0, 0);
      }
    }
  }

  // epilogue: normalize, write head block
  #pragma unroll
  for (int t = 0; t < 4; ++t) {
    const int grow = w * 16 + orow + t;
    const float inv = 1.f / lstate[t];
    unsigned short* og = vals + (size_t)(b * 64 + grow) * DMODEL + h * 64;
    #pragma unroll
    for (int ni = 0; ni < 4; ++ni)
      og[ni * 16 + fr] = f2bf(oacc[ni][t] * inv);
  }
}

// ---------------------------------------------------------------------------
// LayerNorm over D=512 with fused residual add. One wave per row, 8 elems/lane.
// proj input is bf16. resid32 XOR resid16 non-null; out16 and/or out32.
// ---------------------------------------------------------------------------
__global__ __launch_bounds__(256)
void ln_kernel(const unsigned short* __restrict__ proj16, const float* __restrict__ resid32,
               const unsigned short* __restrict__ resid16,
               const float* __restrict__ gamma, const float* __restrict__ beta,
               unsigned short* __restrict__ out16, float* __restrict__ out32)
{
  const int w = threadIdx.x >> 6, lane = threadIdx.x & 63;
  const size_t r = (size_t)blockIdx.x * 4 + w;
  const int d0 = lane * 8;

  float x[8];
  {
    uint4 u = *(const uint4*)(proj16 + r * DMODEL + d0);
    const unsigned short* s = (const unsigned short*)&u;
    #pragma unroll
    for (int j = 0; j < 8; ++j) x[j] = bf2f(s[j]);
  }
  if (resid32) {
    const float* p = resid32 + r * DMODEL + d0;
    float4 a = *(const float4*)p, b = *(const float4*)(p + 4);
    x[0] += a.x; x[1] += a.y; x[2] += a.z; x[3] += a.w;
    x[4] += b.x; x[5] += b.y; x[6] += b.z; x[7] += b.w;
  } else {
    uint4 u = *(const uint4*)(resid16 + r * DMODEL + d0);
    const unsigned short* s = (const unsigned short*)&u;
    #pragma unroll
    for (int j = 0; j < 8; ++j) x[j] += bf2f(s[j]);
  }

  float sum = 0.f;
  #pragma unroll
  for (int j = 0; j < 8; ++j) sum += x[j];
  #pragma unroll
  for (int off = 32; off > 0; off >>= 1) sum += __shfl_xor(sum, off);
  const float mean = sum * (1.f / DMODEL);

  float vs = 0.f;
  #pragma unroll
  for (int j = 0; j < 8; ++j) { float t = x[j] - mean; vs += t * t; }
  #pragma unroll
  for (int off = 32; off > 0; off >>= 1) vs += __shfl_xor(vs, off);
  const float rstd = rsqrtf(vs * (1.f / DMODEL) + 1e-5f);

  float4 g0 = *(const float4*)(gamma + d0), g1 = *(const float4*)(gamma + d0 + 4);
  float4 b0 = *(const float4*)(beta + d0),  b1 = *(const float4*)(beta + d0 + 4);
  const float g[8]  = {g0.x, g0.y, g0.z, g0.w, g1.x, g1.y, g1.z, g1.w};
  const float bb[8] = {b0.x, b0.y, b0.z, b0.w, b1.x, b1.y, b1.z, b1.w};
  float y[8];
  #pragma unroll
  for (int j = 0; j < 8; ++j) y[j] = g[j] * (x[j] - mean) * rstd + bb[j];

  if (out16) {
    union { unsigned short s[8]; uint4 v; } p;
    #pragma unroll
    for (int j = 0; j < 8; ++j) p.s[j] = f2bf(y[j]);
    *(uint4*)(out16 + r * DMODEL + d0) = p.v;
  }
  if (out32) {
    float* o = out32 + r * DMODEL + d0;
    *(float4*)o       = (float4){y[0], y[1], y[2], y[3]};
    *(float4*)(o + 4) = (float4){y[4], y[5], y[6], y[7]};
  }
}

// ---------------------------------------------------------------------------
// Transpose + f32->bf16 convert: W[K,N] f32 -> Wt[N,K] bf16. 32x32 LDS tiles.
// ---------------------------------------------------------------------------
__global__ __launch_bounds__(256)
void transpose_cvt(const float* __restrict__ W, unsigned short* __restrict__ Wt,
                   int K, int N)
{
  __shared__ float tile[32][33];
  const int tx = threadIdx.x, ty = threadIdx.y;
  const int n = blockIdx.x * 32 + tx;
  #pragma unroll
  for (int rr = 0; rr < 4; ++rr) {
    const int k = blockIdx.y * 32 + ty + rr * 8;
    tile[ty + rr * 8][tx] = W[(size_t)k * N + n];
  }
  __syncthreads();
  const int k2 = blockIdx.y * 32 + tx;
  #pragma unroll
  for (int rr = 0; rr < 4; ++rr) {
    const int n2 = blockIdx.x * 32 + ty + rr * 8;
    Wt[(size_t)n2 * K + k2] = f2bf(tile[tx][ty + rr * 8]);
  }
}

// ---------------------------------------------------------------------------
extern "C" void kernel_launch(void* const* d_in, const int* in_sizes, int n_in,
                              void* d_out, int out_size, void* d_ws, size_t ws_size,
                              hipStream_t stream)
{
  const float* x        = (const float*)d_in[0];
  const float* y        = (const float*)d_in[1];
  const float* mask     = (const float*)d_in[2];
  const float* mask2    = (const float*)d_in[3];
  const float* qkv_w    = (const float*)d_in[4];
  const float* qkv_b    = (const float*)d_in[5];
  const float* sa_out_w = (const float*)d_in[6];
  const float* sa_out_b = (const float*)d_in[7];
  const float* q_w      = (const float*)d_in[8];
  const float* q_b      = (const float*)d_in[9];
  const float* kv_w     = (const float*)d_in[10];
  const float* kv_b     = (const float*)d_in[11];
  const float* ca_out_w = (const float*)d_in[12];
  const float* ca_out_b = (const float*)d_in[13];
  const float* l1_w     = (const float*)d_in[14];
  const float* l1_b     = (const float*)d_in[15];
  const float* l2_w     = (const float*)d_in[16];
  const float* l2_b     = (const float*)d_in[17];
  const float* g1 = (const float*)d_in[18];
  const float* b1 = (const float*)d_in[19];
  const float* g2 = (const float*)d_in[20];
  const float* b2 = (const float*)d_in[21];
  const float* g3 = (const float*)d_in[22];
  const float* b3 = (const float*)d_in[23];

  const int B  = in_sizes[1] / (SDEC * DMODEL);   // 256
  const int M  = B * SDEC;                        // 16384 decoder tokens
  const int ME = B * SENC;                        // 131072 encoder tokens

  char* ws = (char*)d_ws;
  size_t off = 0;
  auto alloc = [&](size_t bytes) -> char* {
    char* p = ws + off;
    off += (bytes + 255) & ~(size_t)255;
    return p;
  };
  // persistent regions
  unsigned short* qkv_wt = (unsigned short*)alloc((size_t)1536 * 512 * 2);
  unsigned short* sa_wt  = (unsigned short*)alloc((size_t)512 * 512 * 2);
  unsigned short* q_wt   = (unsigned short*)alloc((size_t)512 * 512 * 2);
  unsigned short* kv_wt  = (unsigned short*)alloc((size_t)1024 * 512 * 2);
  unsigned short* ca_wt  = (unsigned short*)alloc((size_t)512 * 512 * 2);
  unsigned short* l1_wt  = (unsigned short*)alloc((size_t)2048 * 512 * 2);
  unsigned short* l2_wt  = (unsigned short*)alloc((size_t)512 * 2048 * 2);
  unsigned short* kvb    = (unsigned short*)alloc((size_t)ME * 1024 * 2);  // 256 MiB
  char*           xreg   = alloc((size_t)ME * 512 * 2);                    // 128 MiB region
  // xreg aliases (xb dead after kv gemm; qkvb dead after self-attn):
  unsigned short* xb     = (unsigned short*)xreg;
  unsigned short* qkvb   = (unsigned short*)xreg;                          // 48 MiB
  unsigned short* qb     = (unsigned short*)xreg;                          // 16 MiB (after self-attn)
  unsigned short* y2b    = (unsigned short*)(xreg + (size_t)16777216);     // @16 MiB
  unsigned short* valsb  = (unsigned short*)(xreg + (size_t)50331648);     // @48 MiB
  unsigned short* proj   = (unsigned short*)(xreg + (size_t)67108864);     // @64 MiB (bf16)
  unsigned short* y1b    = (unsigned short*)(xreg + (size_t)100663296);    // @96 MiB
  unsigned short* yb     = (unsigned short*)(xreg + (size_t)117440512);    // @112 MiB
  unsigned short* hb     = kvb;  // FFN hidden aliases kv (kv dead after cross-attn)
  (void)ws_size; (void)n_in; (void)out_size;

  // --- weight transposes (f32 [K,N] -> bf16 [N,K]) ---
  dim3 tb(32, 8);
  transpose_cvt<<<dim3(1536 / 32, 512 / 32), tb, 0, stream>>>(qkv_w, qkv_wt, 512, 1536);
  transpose_cvt<<<dim3(512 / 32, 512 / 32), tb, 0, stream>>>(sa_out_w, sa_wt, 512, 512);
  transpose_cvt<<<dim3(512 / 32, 512 / 32), tb, 0, stream>>>(q_w, q_wt, 512, 512);
  transpose_cvt<<<dim3(1024 / 32, 512 / 32), tb, 0, stream>>>(kv_w, kv_wt, 512, 1024);
  transpose_cvt<<<dim3(512 / 32, 512 / 32), tb, 0, stream>>>(ca_out_w, ca_wt, 512, 512);
  transpose_cvt<<<dim3(2048 / 32, 512 / 32), tb, 0, stream>>>(l1_w, l1_wt, 512, 2048);
  transpose_cvt<<<dim3(512 / 32, 2048 / 32), tb, 0, stream>>>(l2_w, l2_wt, 2048, 512);

  const float scale = 0.125f;  // 1/sqrt(64)

  // --- kv projection (x -> bf16, then 256-tile GEMM; xb dead afterwards) ---
  cvt_f32_bf16<<<4096, 256, 0, stream>>>(x, xb, (size_t)ME * 512 / 8);
  gemm256_kernel<0><<<dim3(1024 / 256, ME / 256), 512, 0, stream>>>(xb, kv_wt, kv_b, kvb, ME, 1024, 512);

  // --- self attention ---
  cvt_f32_bf16<<<4096, 256, 0, stream>>>(y, yb, (size_t)M * 512 / 8);
  gemm256_kernel<0><<<dim3(1536 / 256, M / 256), 512, 0, stream>>>(yb, qkv_wt, qkv_b, qkvb, M, 1536, 512);
  // qkv row layout per token: head h -> [h*192 .. ): q(64) | k(64) | v(64)
  attn_mfma<<<dim3(8, B), 256, 0, stream>>>(qkvb, 1536, 192, qkvb, 1536, 192, 64, SDEC, SDEC, mask, valsb, scale);
  gemm_kernel<0><<<dim3(512 / 128, M / 128), 256, 0, stream>>>(valsb, sa_wt, sa_out_b, proj, M, 512, 512);
  ln_kernel<<<M / 4, 256, 0, stream>>>(proj, y, nullptr, g1, b1, y1b, nullptr);

  // --- cross attention ---
  gemm_kernel<0><<<dim3(512 / 128, M / 128), 256, 0, stream>>>(y1b, q_wt, q_b, qb, M, 512, 512);
  // kv row layout per token: head h -> [h*128 .. ): k(64) | v(64)
  attn_mfma<<<dim3(8, B), 256, 0, stream>>>(qb, 512, 64, kvb, 1024, 128, 0, SENC, SENC, mask2, valsb, scale);
  gemm_kernel<0><<<dim3(512 / 128, M / 128), 256, 0, stream>>>(valsb, ca_wt, ca_out_b, proj, M, 512, 512);
  ln_kernel<<<M / 4, 256, 0, stream>>>(proj, nullptr, y1b, g2, b2, y2b, nullptr);

  // --- FFN ---
  gemm256_kernel<1><<<dim3(2048 / 256, M / 256), 512, 0, stream>>>(y2b, l1_wt, l1_b, hb, M, 2048, 512);
  gemm_kernel<0><<<dim3(512 / 128, M / 128), 256, 0, stream>>>(hb, l2_wt, l2_b, proj, M, 512, 2048);
  ln_kernel<<<M / 4, 256, 0, stream>>>(proj, nullptr, y2b, g3, b3, nullptr, (float*)d_out);
}

// Round 8
// 607.030 us; speedup vs baseline: 1.0521x; 1.0280x over previous
//
#include <hip/hip_runtime.h>
#include <hip/hip_bf16.h>
#include <stdint.h>

// Transformer decoder layer: B=256, Sd=64, Se=512, D=512, H=8, HD=64, FF=2048.
// f32 in/out; internal compute bf16 MFMA (tolerance is 2% of ref absmax).

#define SDEC 64
#define SENC 512
#define DMODEL 512
#define FFDIM 2048

typedef __bf16 bf16x8 __attribute__((ext_vector_type(8)));
typedef float  f32x4  __attribute__((ext_vector_type(4)));

static __device__ __forceinline__ float bf2f(unsigned short u) {
  union { unsigned int i; float f; } w; w.i = ((unsigned int)u) << 16; return w.f;
}
static __device__ __forceinline__ unsigned short f2bf(float f) {
  union { float f; unsigned int i; } w; w.f = f;
  unsigned int u = w.i;
  return (unsigned short)((u + 0x7fffu + ((u >> 16) & 1u)) >> 16);  // RTNE
}

// Async global->LDS, 16B per lane. LDS dest = wave-uniform base + lane*16.
static __device__ __forceinline__ void gl_lds16(const unsigned short* g, unsigned short* l) {
  __builtin_amdgcn_global_load_lds(
      (const __attribute__((address_space(1))) unsigned int*)g,
      (__attribute__((address_space(3))) unsigned int*)l,
      16, 0, 0);
}

// ---------------------------------------------------------------------------
// f32 -> bf16 elementwise convert (RTNE), 8 elems/thread/iter, grid-stride.
// ---------------------------------------------------------------------------
__global__ __launch_bounds__(256)
void cvt_f32_bf16(const float* __restrict__ in, unsigned short* __restrict__ out, size_t n8)
{
  size_t i = (size_t)blockIdx.x * blockDim.x + threadIdx.x;
  const size_t stride = (size_t)gridDim.x * blockDim.x;
  for (; i < n8; i += stride) {
    const float* p = in + i * 8;
    float4 a = *(const float4*)p, b = *(const float4*)(p + 4);
    union { unsigned short s[8]; uint4 v; } u;
    u.s[0] = f2bf(a.x); u.s[1] = f2bf(a.y); u.s[2] = f2bf(a.z); u.s[3] = f2bf(a.w);
    u.s[4] = f2bf(b.x); u.s[5] = f2bf(b.y); u.s[6] = f2bf(b.z); u.s[7] = f2bf(b.w);
    *(uint4*)(out + i * 8) = u.v;
  }
}

// ---------------------------------------------------------------------------
// 128x128 GEMM. R4 structure (2-buffer dbuf, gl_lds w=16, counted vmcnt(4),
// raw s_barrier, 3+ blocks/CU) + CORRECT T2 swizzle (R7-verified mechanism,
// re-derived for the [128][32]-bf16 tile):
//   phys 16B-chunk = logical_chunk ^ ((row>>1)&3)   (row-dependent bijection)
//   staging: gl_lds writes linearly; per-lane GLOBAL col pre-swizzled:
//     lane l covers (row rbase + l>>2, phys chunk l&3) -> global chunk
//     (l&3) ^ ((l>>3)&3)                              (rbase % 16 == 0)
//   fragment reads apply the same XOR -> ds_read_b128 at the conflict-free
//   b128 minimum (8 lanes/quad uniform), was 8-way.
// Epilogue swizzle (R6-verified): phys col = c ^ (fq<<4).
// XCD-chunked block swizzle (grid % 8 == 0 for all launches here).
// ---------------------------------------------------------------------------
#define GEMM_COMPUTE(asrc, bsrc)                                                     \
  {                                                                                  \
    const unsigned short* as_ = (asrc);                                              \
    const unsigned short* bs_ = (bsrc);                                              \
    bf16x8 af[4], bfr[4];                                                            \
    _Pragma("unroll")                                                                \
    for (int mi = 0; mi < 4; ++mi)                                                   \
      af[mi] = *(const bf16x8*)&as_[(wm * 64 + mi * 16 + fr) * 32 + fsw];            \
    _Pragma("unroll")                                                                \
    for (int ni = 0; ni < 4; ++ni)                                                   \
      bfr[ni] = *(const bf16x8*)&bs_[(wn * 64 + ni * 16 + fr) * 32 + fsw];           \
    _Pragma("unroll")                                                                \
    for (int mi = 0; mi < 4; ++mi)                                                   \
      _Pragma("unroll")                                                              \
      for (int ni = 0; ni < 4; ++ni)                                                 \
        acc[mi][ni] = __builtin_amdgcn_mfma_f32_16x16x32_bf16(af[mi], bfr[ni],       \
                                                              acc[mi][ni], 0, 0, 0); \
  }

template<int RELU>
__global__ __launch_bounds__(256, 2)
void gemm_kernel(const unsigned short* __restrict__ A, const unsigned short* __restrict__ Bt,
                 const float* __restrict__ bias, unsigned short* __restrict__ C,
                 int M, int N, int K)
{
  __shared__ unsigned short sh[2 * 8192];   // 2 bufs x (A 8KB | B 8KB) = 32 KB
  const int tid = threadIdx.x;

  const int gx   = gridDim.x;
  const int nwg  = gx * gridDim.y;
  const int orig = blockIdx.y * gx + blockIdx.x;
  const int wg   = (orig & 7) * (nwg >> 3) + (orig >> 3);
  const int row0 = (wg / gx) * 128;
  const int col0 = (wg % gx) * 128;

  const int w = tid >> 6, lane = tid & 63;
  const int wm = w >> 1, wn = w & 1;
  const int gr = lane >> 2;
  const int gc = ((lane & 3) ^ ((lane >> 3) & 3)) * 8;   // pre-swizzled global chunk

  auto STAGE = [&](int k0, int buf) {
    unsigned short* as = sh + buf * 8192;
    unsigned short* bs = as + 4096;
    #pragma unroll
    for (int i = 0; i < 2; ++i) {
      const int rbase = w * 32 + i * 16;   // wave-uniform, % 16 == 0
      gl_lds16(A  + (size_t)(row0 + rbase + gr) * K + (k0 + gc), as + rbase * 32);
      gl_lds16(Bt + (size_t)(col0 + rbase + gr) * K + (k0 + gc), bs + rbase * 32);
    }
  };

  f32x4 acc[4][4];
  #pragma unroll
  for (int i = 0; i < 4; ++i)
    #pragma unroll
    for (int j = 0; j < 4; ++j)
      acc[i][j] = (f32x4){0.f, 0.f, 0.f, 0.f};

  const int fr  = lane & 15;
  const int fg  = lane >> 4;
  const int fsw = (fg ^ ((fr >> 1) & 3)) * 8;   // swizzled fragment chunk offset

  STAGE(0, 0);
  int cur = 0;
  for (int k0 = 0; k0 + 32 < K; k0 += 32) {
    STAGE(k0 + 32, cur ^ 1);                          // prefetch next tile
    asm volatile("s_waitcnt vmcnt(4)" ::: "memory");  // own tile's loads done
    __builtin_amdgcn_s_barrier();                     // all waves: tile visible
    asm volatile("" ::: "memory");
    GEMM_COMPUTE(sh + cur * 8192, sh + cur * 8192 + 4096);
    asm volatile("" ::: "memory");
    __builtin_amdgcn_s_barrier();                     // reads of buf[cur] done
    cur ^= 1;
  }
  asm volatile("s_waitcnt vmcnt(0)" ::: "memory");
  __builtin_amdgcn_s_barrier();
  asm volatile("" ::: "memory");
  GEMM_COMPUTE(sh + cur * 8192, sh + cur * 8192 + 4096);
  asm volatile("" ::: "memory");
  __builtin_amdgcn_s_barrier();   // LDS free for epilogue reuse

  // Epilogue: LDS-staged, swizzled (phys col = c ^ (fq<<4); 2-way = free).
  {
    const int fq = lane >> 4;
    #pragma unroll
    for (int ni = 0; ni < 4; ++ni) {
      const int c = wn * 64 + ni * 16 + fr;
      const float bv = bias ? bias[col0 + c] : 0.f;
      #pragma unroll
      for (int mi = 0; mi < 4; ++mi) {
        #pragma unroll
        for (int t = 0; t < 4; ++t) {
          const int r = wm * 64 + mi * 16 + fq * 4 + t;
          float v = acc[mi][ni][t] + bv;
          if (RELU) v = fmaxf(v, 0.f);
          sh[r * 128 + (c ^ (fq << 4))] = f2bf(v);
        }
      }
    }
    __syncthreads();
    const int rr = tid >> 4;
    const int cc = (tid & 15) * 8;
    #pragma unroll
    for (int p = 0; p < 8; ++p) {
      const int r = p * 16 + rr;
      *(uint4*)(C + (size_t)(row0 + r) * N + col0 + cc) =
          *(const uint4*)&sh[r * 128 + (cc ^ (w << 4))];
    }
  }
}

// ---------------------------------------------------------------------------
// MFMA flash attention. One block (4 waves) per (b,h). 64 query rows, HD=64.
// XCD-chunked swizzle so same-b blocks share an XCD's L2 (KV + mask reuse).
// ---------------------------------------------------------------------------
__global__ __launch_bounds__(256, 2)
void attn_mfma(const unsigned short* __restrict__ qbuf, int qstride, int qmul,
               const unsigned short* __restrict__ kvbuf, int kvstride, int kmul, int kadd,
               int tokmul, int Skv, const float* __restrict__ mask,
               unsigned short* __restrict__ vals, float scale)
{
  __shared__ unsigned short Qs[64 * 72];   // pad 72 shorts: 144B rows, 16B-aligned
  __shared__ unsigned short Ks[64 * 72];
  __shared__ unsigned short Vt[64 * 72];   // [d][j] (transposed V tile)
  __shared__ unsigned short Ps[64 * 72];   // [row][j], wave-private 16-row slabs

  const int nwg  = gridDim.x * gridDim.y;          // 8 * B, % 8 == 0
  const int orig = blockIdx.y * gridDim.x + blockIdx.x;
  const int wg   = (orig & 7) * (nwg >> 3) + (orig >> 3);
  const int h = wg & 7, b = wg >> 3;

  const int tid = threadIdx.x;
  const int w = tid >> 6, lane = tid & 63;
  const int srow = tid >> 2;          // 0..63 staging row (token)
  const int sc0 = (tid & 3) * 16;     // 0,16,32,48 staging col (d)

  // stage Q once
  {
    const unsigned short* qg = qbuf + (size_t)(b * 64 + srow) * qstride + h * qmul + sc0;
    *(uint4*)&Qs[srow * 72 + sc0]     = *(const uint4*)qg;
    *(uint4*)&Qs[srow * 72 + sc0 + 8] = *(const uint4*)(qg + 8);
  }

  const int fr = lane & 15;    // A/B frag row index
  const int fg = lane >> 4;    // frag k-group
  const int orow = fg * 4;     // C/D row base within 16-slice

  float mstate[4], lstate[4];
  f32x4 oacc[4];
  #pragma unroll
  for (int t = 0; t < 4; ++t) { mstate[t] = -1e30f; lstate[t] = 0.f; }
  #pragma unroll
  for (int ni = 0; ni < 4; ++ni) oacc[ni] = (f32x4){0.f, 0.f, 0.f, 0.f};

  for (int j0 = 0; j0 < Skv; j0 += 64) {
    __syncthreads();  // prior tile's K/V reads complete (covers Q on iter 0)
    {
      const unsigned short* kg = kvbuf + (size_t)(b * tokmul + j0 + srow) * kvstride
                                 + h * kmul + kadd + sc0;
      *(uint4*)&Ks[srow * 72 + sc0]     = *(const uint4*)kg;
      *(uint4*)&Ks[srow * 72 + sc0 + 8] = *(const uint4*)(kg + 8);
      const unsigned short* vg = kg + 64;  // V sits 64 shorts after K
      uint4 v0 = *(const uint4*)vg;
      uint4 v1 = *(const uint4*)(vg + 8);
      const unsigned short* vsp = (const unsigned short*)&v0;
      #pragma unroll
      for (int jj = 0; jj < 8; ++jj) Vt[(sc0 + jj) * 72 + srow] = vsp[jj];
      vsp = (const unsigned short*)&v1;
      #pragma unroll
      for (int jj = 0; jj < 8; ++jj) Vt[(sc0 + 8 + jj) * 72 + srow] = vsp[jj];
    }
    __syncthreads();

    // S = Q @ K^T  (wave's 16-row slice x 64 key cols)
    f32x4 s[4];
    #pragma unroll
    for (int ni = 0; ni < 4; ++ni) s[ni] = (f32x4){0.f, 0.f, 0.f, 0.f};
    #pragma unroll
    for (int ks = 0; ks < 2; ++ks) {
      bf16x8 aq = *(const bf16x8*)&Qs[(w * 16 + fr) * 72 + ks * 32 + fg * 8];
      #pragma unroll
      for (int ni = 0; ni < 4; ++ni) {
        bf16x8 bk = *(const bf16x8*)&Ks[(ni * 16 + fr) * 72 + ks * 32 + fg * 8];
        s[ni] = __builtin_amdgcn_mfma_f32_16x16x32_bf16(aq, bk, s[ni], 0, 0, 0);
      }
    }

    // online softmax (each lane owns rows orow..orow+3 of the wave slice)
    #pragma unroll
    for (int t = 0; t < 4; ++t) {
      const int grow = w * 16 + orow + t;
      const float* mrow = mask + ((size_t)b * 64 + grow) * Skv + j0;
      float sv[4];
      float tmax = -1e30f;
      #pragma unroll
      for (int ni = 0; ni < 4; ++ni) {
        sv[ni] = s[ni][t] * scale + mrow[ni * 16 + fr];
        tmax = fmaxf(tmax, sv[ni]);
      }
      #pragma unroll
      for (int off = 1; off < 16; off <<= 1) tmax = fmaxf(tmax, __shfl_xor(tmax, off));
      const float mn = fmaxf(mstate[t], tmax);
      const float fscl = __expf(mstate[t] - mn);
      mstate[t] = mn;
      float psum = 0.f;
      #pragma unroll
      for (int ni = 0; ni < 4; ++ni) {
        float p = __expf(sv[ni] - mn);
        psum += p;
        Ps[grow * 72 + ni * 16 + fr] = f2bf(p);
      }
      #pragma unroll
      for (int off = 1; off < 16; off <<= 1) psum += __shfl_xor(psum, off);
      lstate[t] = lstate[t] * fscl + psum;
      #pragma unroll
      for (int ni = 0; ni < 4; ++ni) oacc[ni][t] *= fscl;
    }
    __syncthreads();  // Ps visible (cross-lane), Vt/Ks stable

    // O += P @ V   (A = P rows, B = Vt rows)
    #pragma unroll
    for (int ks = 0; ks < 2; ++ks) {
      bf16x8 pa = *(const bf16x8*)&Ps[(w * 16 + fr) * 72 + ks * 32 + fg * 8];
      #pragma unroll
      for (int ni = 0; ni < 4; ++ni) {
        bf16x8 vb = *(const bf16x8*)&Vt[(ni * 16 + fr) * 72 + ks * 32 + fg * 8];
        oacc[ni] = __builtin_amdgcn_mfma_f32_16x16x32_bf16(pa, vb, oacc[ni], 0, 0, 0);
      }
    }
  }

  // epilogue: normalize, write head block
  #pragma unroll
  for (int t = 0; t < 4; ++t) {
    const int grow = w * 16 + orow + t;
    const float inv = 1.f / lstate[t];
    unsigned short* og = vals + (size_t)(b * 64 + grow) * DMODEL + h * 64;
    #pragma unroll
    for (int ni = 0; ni < 4; ++ni)
      og[ni * 16 + fr] = f2bf(oacc[ni][t] * inv);
  }
}

// ---------------------------------------------------------------------------
// LayerNorm over D=512 with fused residual add. One wave per row, 8 elems/lane.
// proj input is bf16. resid32 XOR resid16 non-null; out16 and/or out32.
// ---------------------------------------------------------------------------
__global__ __launch_bounds__(256)
void ln_kernel(const unsigned short* __restrict__ proj16, const float* __restrict__ resid32,
               const unsigned short* __restrict__ resid16,
               const float* __restrict__ gamma, const float* __restrict__ beta,
               unsigned short* __restrict__ out16, float* __restrict__ out32)
{
  const int w = threadIdx.x >> 6, lane = threadIdx.x & 63;
  const size_t r = (size_t)blockIdx.x * 4 + w;
  const int d0 = lane * 8;

  float x[8];
  {
    uint4 u = *(const uint4*)(proj16 + r * DMODEL + d0);
    const unsigned short* s = (const unsigned short*)&u;
    #pragma unroll
    for (int j = 0; j < 8; ++j) x[j] = bf2f(s[j]);
  }
  if (resid32) {
    const float* p = resid32 + r * DMODEL + d0;
    float4 a = *(const float4*)p, b = *(const float4*)(p + 4);
    x[0] += a.x; x[1] += a.y; x[2] += a.z; x[3] += a.w;
    x[4] += b.x; x[5] += b.y; x[6] += b.z; x[7] += b.w;
  } else {
    uint4 u = *(const uint4*)(resid16 + r * DMODEL + d0);
    const unsigned short* s = (const unsigned short*)&u;
    #pragma unroll
    for (int j = 0; j < 8; ++j) x[j] += bf2f(s[j]);
  }

  float sum = 0.f;
  #pragma unroll
  for (int j = 0; j < 8; ++j) sum += x[j];
  #pragma unroll
  for (int off = 32; off > 0; off >>= 1) sum += __shfl_xor(sum, off);
  const float mean = sum * (1.f / DMODEL);

  float vs = 0.f;
  #pragma unroll
  for (int j = 0; j < 8; ++j) { float t = x[j] - mean; vs += t * t; }
  #pragma unroll
  for (int off = 32; off > 0; off >>= 1) vs += __shfl_xor(vs, off);
  const float rstd = rsqrtf(vs * (1.f / DMODEL) + 1e-5f);

  float4 g0 = *(const float4*)(gamma + d0), g1 = *(const float4*)(gamma + d0 + 4);
  float4 b0 = *(const float4*)(beta + d0),  b1 = *(const float4*)(beta + d0 + 4);
  const float g[8]  = {g0.x, g0.y, g0.z, g0.w, g1.x, g1.y, g1.z, g1.w};
  const float bb[8] = {b0.x, b0.y, b0.z, b0.w, b1.x, b1.y, b1.z, b1.w};
  float y[8];
  #pragma unroll
  for (int j = 0; j < 8; ++j) y[j] = g[j] * (x[j] - mean) * rstd + bb[j];

  if (out16) {
    union { unsigned short s[8]; uint4 v; } p;
    #pragma unroll
    for (int j = 0; j < 8; ++j) p.s[j] = f2bf(y[j]);
    *(uint4*)(out16 + r * DMODEL + d0) = p.v;
  }
  if (out32) {
    float* o = out32 + r * DMODEL + d0;
    *(float4*)o       = (float4){y[0], y[1], y[2], y[3]};
    *(float4*)(o + 4) = (float4){y[4], y[5], y[6], y[7]};
  }
}

// ---------------------------------------------------------------------------
// Transpose + f32->bf16 convert: W[K,N] f32 -> Wt[N,K] bf16. 32x32 LDS tiles.
// ---------------------------------------------------------------------------
__global__ __launch_bounds__(256)
void transpose_cvt(const float* __restrict__ W, unsigned short* __restrict__ Wt,
                   int K, int N)
{
  __shared__ float tile[32][33];
  const int tx = threadIdx.x, ty = threadIdx.y;
  const int n = blockIdx.x * 32 + tx;
  #pragma unroll
  for (int rr = 0; rr < 4; ++rr) {
    const int k = blockIdx.y * 32 + ty + rr * 8;
    tile[ty + rr * 8][tx] = W[(size_t)k * N + n];
  }
  __syncthreads();
  const int k2 = blockIdx.y * 32 + tx;
  #pragma unroll
  for (int rr = 0; rr < 4; ++rr) {
    const int n2 = blockIdx.x * 32 + ty + rr * 8;
    Wt[(size_t)n2 * K + k2] = f2bf(tile[tx][ty + rr * 8]);
  }
}

// ---------------------------------------------------------------------------
extern "C" void kernel_launch(void* const* d_in, const int* in_sizes, int n_in,
                              void* d_out, int out_size, void* d_ws, size_t ws_size,
                              hipStream_t stream)
{
  const float* x        = (const float*)d_in[0];
  const float* y        = (const float*)d_in[1];
  const float* mask     = (const float*)d_in[2];
  const float* mask2    = (const float*)d_in[3];
  const float* qkv_w    = (const float*)d_in[4];
  const float* qkv_b    = (const float*)d_in[5];
  const float* sa_out_w = (const float*)d_in[6];
  const float* sa_out_b = (const float*)d_in[7];
  const float* q_w      = (const float*)d_in[8];
  const float* q_b      = (const float*)d_in[9];
  const float* kv_w     = (const float*)d_in[10];
  const float* kv_b     = (const float*)d_in[11];
  const float* ca_out_w = (const float*)d_in[12];
  const float* ca_out_b = (const float*)d_in[13];
  const float* l1_w     = (const float*)d_in[14];
  const float* l1_b     = (const float*)d_in[15];
  const float* l2_w     = (const float*)d_in[16];
  const float* l2_b     = (const float*)d_in[17];
  const float* g1 = (const float*)d_in[18];
  const float* b1 = (const float*)d_in[19];
  const float* g2 = (const float*)d_in[20];
  const float* b2 = (const float*)d_in[21];
  const float* g3 = (const float*)d_in[22];
  const float* b3 = (const float*)d_in[23];

  const int B  = in_sizes[1] / (SDEC * DMODEL);   // 256
  const int M  = B * SDEC;                        // 16384 decoder tokens
  const int ME = B * SENC;                        // 131072 encoder tokens

  char* ws = (char*)d_ws;
  size_t off = 0;
  auto alloc = [&](size_t bytes) -> char* {
    char* p = ws + off;
    off += (bytes + 255) & ~(size_t)255;
    return p;
  };
  // persistent regions
  unsigned short* qkv_wt = (unsigned short*)alloc((size_t)1536 * 512 * 2);
  unsigned short* sa_wt  = (unsigned short*)alloc((size_t)512 * 512 * 2);
  unsigned short* q_wt   = (unsigned short*)alloc((size_t)512 * 512 * 2);
  unsigned short* kv_wt  = (unsigned short*)alloc((size_t)1024 * 512 * 2);
  unsigned short* ca_wt  = (unsigned short*)alloc((size_t)512 * 512 * 2);
  unsigned short* l1_wt  = (unsigned short*)alloc((size_t)2048 * 512 * 2);
  unsigned short* l2_wt  = (unsigned short*)alloc((size_t)512 * 2048 * 2);
  unsigned short* kvb    = (unsigned short*)alloc((size_t)ME * 1024 * 2);  // 256 MiB
  char*           xreg   = alloc((size_t)ME * 512 * 2);                    // 128 MiB region
  // xreg aliases (xb dead after kv gemm; qkvb dead after self-attn):
  unsigned short* xb     = (unsigned short*)xreg;
  unsigned short* qkvb   = (unsigned short*)xreg;                          // 48 MiB
  unsigned short* qb     = (unsigned short*)xreg;                          // 16 MiB (after self-attn)
  unsigned short* y2b    = (unsigned short*)(xreg + (size_t)16777216);     // @16 MiB
  unsigned short* valsb  = (unsigned short*)(xreg + (size_t)50331648);     // @48 MiB
  unsigned short* proj   = (unsigned short*)(xreg + (size_t)67108864);     // @64 MiB (bf16)
  unsigned short* y1b    = (unsigned short*)(xreg + (size_t)100663296);    // @96 MiB
  unsigned short* yb     = (unsigned short*)(xreg + (size_t)117440512);    // @112 MiB
  unsigned short* hb     = kvb;  // FFN hidden aliases kv (kv dead after cross-attn)
  (void)ws_size; (void)n_in; (void)out_size;

  // --- weight transposes (f32 [K,N] -> bf16 [N,K]) ---
  dim3 tb(32, 8);
  transpose_cvt<<<dim3(1536 / 32, 512 / 32), tb, 0, stream>>>(qkv_w, qkv_wt, 512, 1536);
  transpose_cvt<<<dim3(512 / 32, 512 / 32), tb, 0, stream>>>(sa_out_w, sa_wt, 512, 512);
  transpose_cvt<<<dim3(512 / 32, 512 / 32), tb, 0, stream>>>(q_w, q_wt, 512, 512);
  transpose_cvt<<<dim3(1024 / 32, 512 / 32), tb, 0, stream>>>(kv_w, kv_wt, 512, 1024);
  transpose_cvt<<<dim3(512 / 32, 512 / 32), tb, 0, stream>>>(ca_out_w, ca_wt, 512, 512);
  transpose_cvt<<<dim3(2048 / 32, 512 / 32), tb, 0, stream>>>(l1_w, l1_wt, 512, 2048);
  transpose_cvt<<<dim3(512 / 32, 2048 / 32), tb, 0, stream>>>(l2_w, l2_wt, 2048, 512);

  const float scale = 0.125f;  // 1/sqrt(64)

  // --- kv projection (x -> bf16, then GEMM; xb dead afterwards) ---
  cvt_f32_bf16<<<4096, 256, 0, stream>>>(x, xb, (size_t)ME * 512 / 8);
  gemm_kernel<0><<<dim3(1024 / 128, ME / 128), 256, 0, stream>>>(xb, kv_wt, kv_b, kvb, ME, 1024, 512);

  // --- self attention ---
  cvt_f32_bf16<<<4096, 256, 0, stream>>>(y, yb, (size_t)M * 512 / 8);
  gemm_kernel<0><<<dim3(1536 / 128, M / 128), 256, 0, stream>>>(yb, qkv_wt, qkv_b, qkvb, M, 1536, 512);
  // qkv row layout per token: head h -> [h*192 .. ): q(64) | k(64) | v(64)
  attn_mfma<<<dim3(8, B), 256, 0, stream>>>(qkvb, 1536, 192, qkvb, 1536, 192, 64, SDEC, SDEC, mask, valsb, scale);
  gemm_kernel<0><<<dim3(512 / 128, M / 128), 256, 0, stream>>>(valsb, sa_wt, sa_out_b, proj, M, 512, 512);
  ln_kernel<<<M / 4, 256, 0, stream>>>(proj, y, nullptr, g1, b1, y1b, nullptr);

  // --- cross attention ---
  gemm_kernel<0><<<dim3(512 / 128, M / 128), 256, 0, stream>>>(y1b, q_wt, q_b, qb, M, 512, 512);
  // kv row layout per token: head h -> [h*128 .. ): k(64) | v(64)
  attn_mfma<<<dim3(8, B), 256, 0, stream>>>(qb, 512, 64, kvb, 1024, 128, 0, SENC, SENC, mask2, valsb, scale);
  gemm_kernel<0><<<dim3(512 / 128, M / 128), 256, 0, stream>>>(valsb, ca_wt, ca_out_b, proj, M, 512, 512);
  ln_kernel<<<M / 4, 256, 0, stream>>>(proj, nullptr, y1b, g2, b2, y2b, nullptr);

  // --- FFN ---
  gemm_kernel<1><<<dim3(2048 / 128, M / 128), 256, 0, stream>>>(y2b, l1_wt, l1_b, hb, M, 2048, 512);
  gemm_kernel<0><<<dim3(512 / 128, M / 128), 256, 0, stream>>>(hb, l2_wt, l2_b, proj, M, 512, 2048);
  ln_kernel<<<M / 4, 256, 0, stream>>>(proj, nullptr, y2b, g3, b3, nullptr, (float*)d_out);
}